// Round 1
// baseline (219.130 us; speedup 1.0000x reference)
//
#include <hip/hip_runtime.h>
#include <math.h>

#define NB 2
#define NT 256
#define NN 512
#define NH 64
#define NS 8
#define NC 8

// workspace layout (float offsets)
#define OFF_DYN   0                        // NB*NN*4    = 4096
#define OFF_H     4096                     // NB*NN*64   = 65536
#define OFF_PREI  (4096 + 65536)           // 65536
#define OFF_PREJ  (4096 + 2*65536)         // 65536
#define OFF_INVN  (4096 + 3*65536)         // 1024
#define OFF_UNSYM (4096 + 3*65536 + 1024)  // NB*NN*NN = 524288
// total = 726016 floats = ~2.9 MB

__device__ __forceinline__ float softplusf(float x){
  if (x > 20.f) return x;
  return log1pf(expf(x));
}

// ---------------- Kernel A: temporal stats -> dyn[b][n][4] ----------------
// grid (NB, NN/16), block 256 = 16 n-lanes x 16 t-slices (16 t each)
__global__ __launch_bounds__(256) void k_stats(
    const float* __restrict__ x, const float* __restrict__ mask,
    float* __restrict__ dyn){
  int b  = blockIdx.x;
  int nl = threadIdx.x & 15;
  int ts = threadIdx.x >> 4;            // 0..15
  int n  = blockIdx.y * 16 + nl;

  float cnt = 0.f, sx = 0.f, sxx = 0.f;
  int lastt = 0;
  for (int t = ts*16; t < ts*16 + 16; ++t){
    int idx = (b*NT + t)*NN + n;
    float xv = x[idx];
    float mv = mask[idx];
    bool obs = (mv < 0.5f);
    if (obs){ cnt += 1.f; sx += xv; sxx += xv*xv; lastt = t; }
  }
  __shared__ float s_cnt[16][16], s_sx[16][16], s_sxx[16][16];
  __shared__ int   s_lt[16][16];
  s_cnt[ts][nl] = cnt; s_sx[ts][nl] = sx; s_sxx[ts][nl] = sxx; s_lt[ts][nl] = lastt;
  __syncthreads();
  if (ts == 0){
    for (int s2 = 1; s2 < 16; ++s2){
      cnt += s_cnt[s2][nl]; sx += s_sx[s2][nl]; sxx += s_sxx[s2][nl];
      lastt = max(lastt, s_lt[s2][nl]);
    }
    float cc   = fmaxf(cnt, 1.f);
    float mean = sx / cc;
    float var  = sxx / cc - mean*mean;
    float stdv = sqrtf(fmaxf(var, 0.f) + 1e-6f);
    float last = x[(b*NT + lastt)*NN + n];
    float mr   = 1.f - cnt * (1.f/(float)NT);
    float* o = dyn + ((b*NN) + n)*4;
    o[0] = mean; o[1] = stdv; o[2] = last; o[3] = mr;
  }
}

// ---------------- Kernel B: node MLP -> h, pre_i, pre_j(+be1), invn ----------------
// grid NB*NN, block 64 (one wave), thread = output channel c
__global__ __launch_bounds__(64) void k_node(
    const float* __restrict__ dyn, const float* __restrict__ sctx,
    const float* __restrict__ W1, const float* __restrict__ b1,
    const float* __restrict__ W2, const float* __restrict__ b2,
    const float* __restrict__ We1, const float* __restrict__ be1,
    float* __restrict__ hg, float* __restrict__ prei,
    float* __restrict__ prej, float* __restrict__ invn){
  int bn = blockIdx.x;            // b*NN + n
  int n  = bn & (NN-1);
  int c  = threadIdx.x;
  __shared__ float feats[12];
  __shared__ float h1[64];
  __shared__ float h2s[64];
  if (c < 4)       feats[c] = dyn[bn*4 + c];
  else if (c < 12) feats[c] = sctx[n*NS + (c-4)];
  __syncthreads();

  float a = b1[c];
  #pragma unroll
  for (int k = 0; k < 12; ++k) a = fmaf(feats[k], W1[k*NH + c], a);
  h1[c] = fmaxf(a, 0.f);
  __syncthreads();

  float a2 = b2[c];
  #pragma unroll 8
  for (int k = 0; k < 64; ++k) a2 = fmaf(h1[k], W2[k*NH + c], a2);
  a2 = fmaxf(a2, 0.f);

  float sq = a2*a2;
  #pragma unroll
  for (int m = 1; m < 64; m <<= 1) sq += __shfl_xor(sq, m);
  float inv = 1.f / fmaxf(sqrtf(sq), 1e-12f);

  h2s[c] = a2;
  __syncthreads();

  float pi = 0.f, pj = be1[c];
  #pragma unroll 8
  for (int k = 0; k < 64; ++k){
    float hk = h2s[k];
    pi = fmaf(hk, We1[k*NH + c],        pi);
    pj = fmaf(hk, We1[(64 + k)*NH + c], pj);
  }
  hg  [bn*64 + c] = a2;
  prei[bn*64 + c] = pi;
  prej[bn*64 + c] = pj;
  if (c == 0) invn[bn] = inv;
}

// ---------------- Kernel C: pairwise edge MLP + logits + row softmax ----------------
// grid NB*NN (one block per (b,i)), block 256 = 4 waves; wave = 4 groups of 16 lanes;
// group handles 4 j's; lane q in group owns channel quad c = 4q..4q+3.
__global__ __launch_bounds__(256) void k_pair(
    const float* __restrict__ hg, const float* __restrict__ prei,
    const float* __restrict__ prej, const float* __restrict__ invn,
    const float* __restrict__ coords,
    const float* __restrict__ We1, const float* __restrict__ We2,
    const float* __restrict__ be2,
    const float* __restrict__ s_sl, const float* __restrict__ s_ps,
    const float* __restrict__ s_ss, const float* __restrict__ s_tp,
    float* __restrict__ unsym){
  int blk = blockIdx.x;
  int b = blk >> 9, i = blk & (NN-1);
  int tid  = threadIdx.x;
  int w    = tid >> 6;
  int lane = tid & 63;
  int g    = lane >> 4;
  int q    = lane & 15;
  int c0   = q * 4;

  const float* Wa = We1 + 128*NH;
  const float* Wp = We1 + 192*NH;

  __shared__ __align__(16) float s_hi[64];
  __shared__ float lrow[NN];
  __shared__ float red[8];

  if (tid < 64) s_hi[tid] = hg[(b*NN + i)*64 + tid];
  __syncthreads();

  float4 pre4  = *(const float4*)(prei + (b*NN + i)*64 + c0);
  float4 we2q  = *(const float4*)(We2 + c0);
  float  invni = invn[b*NN + i];
  float  be2v  = be2[0];
  float cix[8];
  #pragma unroll
  for (int d = 0; d < 8; ++d) cix[d] = coords[i*8 + d];
  float spsl = softplusf(s_sl[0]);
  float spps = softplusf(s_ps[0]);
  float spss = softplusf(s_ss[0]);
  float invt = 1.f / (softplusf(s_tp[0]) + 1e-4f);

  for (int it = 0; it < 8; ++it){
    int jbase = it*64 + w*16 + g*4;
    float acc[4][4];
    float dotv[4];
    #pragma unroll
    for (int m = 0; m < 4; ++m){
      dotv[m] = 0.f;
      #pragma unroll
      for (int cc = 0; cc < 4; ++cc) acc[m][cc] = 0.f;
    }
    const float* hj0 = hg + ((b*NN + jbase) * 64);

    for (int k0 = 0; k0 < 64; k0 += 4){
      float4 hi4 = *(const float4*)(s_hi + k0);
      float4 wa4[4], wp4[4];
      #pragma unroll
      for (int kk = 0; kk < 4; ++kk){
        wa4[kk] = *(const float4*)(Wa + (k0+kk)*NH + c0);
        wp4[kk] = *(const float4*)(Wp + (k0+kk)*NH + c0);
      }
      #pragma unroll
      for (int m = 0; m < 4; ++m){
        float4 hj4 = *(const float4*)(hj0 + m*64 + k0);
        float hi_[4] = {hi4.x, hi4.y, hi4.z, hi4.w};
        float hj_[4] = {hj4.x, hj4.y, hj4.z, hj4.w};
        #pragma unroll
        for (int kk = 0; kk < 4; ++kk){
          float d = fabsf(hi_[kk] - hj_[kk]);
          float p = hi_[kk] * hj_[kk];
          dotv[m] += p;
          acc[m][0] = fmaf(d, wa4[kk].x, acc[m][0]);
          acc[m][1] = fmaf(d, wa4[kk].y, acc[m][1]);
          acc[m][2] = fmaf(d, wa4[kk].z, acc[m][2]);
          acc[m][3] = fmaf(d, wa4[kk].w, acc[m][3]);
          acc[m][0] = fmaf(p, wp4[kk].x, acc[m][0]);
          acc[m][1] = fmaf(p, wp4[kk].y, acc[m][1]);
          acc[m][2] = fmaf(p, wp4[kk].z, acc[m][2]);
          acc[m][3] = fmaf(p, wp4[kk].w, acc[m][3]);
        }
      }
    }

    #pragma unroll
    for (int m = 0; m < 4; ++m){
      int j = jbase + m;
      float4 pj4 = *(const float4*)(prej + (b*NN + j)*64 + c0);
      float t0 = fmaxf(pre4.x + pj4.x + acc[m][0], 0.f);
      float t1 = fmaxf(pre4.y + pj4.y + acc[m][1], 0.f);
      float t2 = fmaxf(pre4.z + pj4.z + acc[m][2], 0.f);
      float t3 = fmaxf(pre4.w + pj4.w + acc[m][3], 0.f);
      float part = t0*we2q.x + t1*we2q.y + t2*we2q.z + t3*we2q.w;
      #pragma unroll
      for (int msk = 1; msk < 16; msk <<= 1) part += __shfl_xor(part, msk);
      if (q == 0){
        float edge = part + be2v;
        float cosv = dotv[m] * invni * invn[b*NN + j];
        float dd = 0.f;
        #pragma unroll
        for (int d2 = 0; d2 < 8; ++d2){
          float df = cix[d2] - coords[j*8 + d2];
          dd = fmaf(df, df, dd);
        }
        float dist  = sqrtf(fmaxf(dd, 1e-12f));
        float prior = 1.f / (1.f + dist);
        float lg = (j == i) ? spsl : (edge + spps*prior + spss*cosv);
        lrow[j] = lg;
      }
    }
  }
  __syncthreads();

  // row softmax of lrow/temp
  float m1 = -INFINITY;
  for (int j = tid; j < NN; j += 256) m1 = fmaxf(m1, lrow[j]);
  #pragma unroll
  for (int msk = 1; msk < 64; msk <<= 1) m1 = fmaxf(m1, __shfl_xor(m1, msk));
  if (lane == 0) red[w] = m1;
  __syncthreads();
  m1 = fmaxf(fmaxf(red[0], red[1]), fmaxf(red[2], red[3]));

  float se = 0.f;
  for (int j = tid; j < NN; j += 256){
    float e = expf((lrow[j] - m1) * invt);
    lrow[j] = e;
    se += e;
  }
  #pragma unroll
  for (int msk = 1; msk < 64; msk <<= 1) se += __shfl_xor(se, msk);
  if (lane == 0) red[4 + w] = se;
  __syncthreads();
  se = red[4] + red[5] + red[6] + red[7];
  float inv_se = 1.f / se;

  float* urow = unsym + (size_t)(b*NN + i) * NN;
  for (int j = tid; j < NN; j += 256) urow[j] = lrow[j] * inv_se;
}

// ---------------- Kernel D: symmetrize + renormalize ----------------
__global__ __launch_bounds__(256) void k_sym(
    const float* __restrict__ u, float* __restrict__ out){
  int blk = blockIdx.x;
  int b = blk >> 9, i = blk & (NN-1);
  int tid = threadIdx.x;
  const float* urow = u + (size_t)(b*NN + i) * NN;
  float v0, v1, rs;
  {
    int j0 = tid, j1 = tid + 256;
    float a1 = urow[j0];
    float a2 = u[(size_t)(b*NN + j0) * NN + i];
    v0 = 0.5f*(a1 + a2);
    float a3 = urow[j1];
    float a4 = u[(size_t)(b*NN + j1) * NN + i];
    v1 = 0.5f*(a3 + a4);
    rs = v0 + v1;
  }
  int lane = tid & 63, w = tid >> 6;
  #pragma unroll
  for (int msk = 1; msk < 64; msk <<= 1) rs += __shfl_xor(rs, msk);
  __shared__ float red[4];
  if (lane == 0) red[w] = rs;
  __syncthreads();
  rs = red[0] + red[1] + red[2] + red[3];
  float inv = 1.f / fmaxf(rs, 1e-6f);
  float* orow = out + (size_t)(b*NN + i) * NN;
  orow[tid]       = v0 * inv;
  orow[tid + 256] = v1 * inv;
}

extern "C" void kernel_launch(void* const* d_in, const int* in_sizes, int n_in,
                              void* d_out, int out_size, void* d_ws, size_t ws_size,
                              hipStream_t stream){
  const float* x      = (const float*)d_in[0];
  const float* mask   = (const float*)d_in[1];
  const float* sctx   = (const float*)d_in[2];
  const float* coords = (const float*)d_in[3];
  const float* W1     = (const float*)d_in[4];
  const float* b1     = (const float*)d_in[5];
  const float* W2     = (const float*)d_in[6];
  const float* b2     = (const float*)d_in[7];
  const float* We1    = (const float*)d_in[8];
  const float* be1    = (const float*)d_in[9];
  const float* We2    = (const float*)d_in[10];
  const float* be2    = (const float*)d_in[11];
  const float* sl     = (const float*)d_in[12];
  const float* ps     = (const float*)d_in[13];
  const float* ss     = (const float*)d_in[14];
  const float* tp     = (const float*)d_in[15];

  float* ws    = (float*)d_ws;
  float* dyn   = ws + OFF_DYN;
  float* hg    = ws + OFF_H;
  float* prei  = ws + OFF_PREI;
  float* prej  = ws + OFF_PREJ;
  float* invnp = ws + OFF_INVN;
  float* unsym = ws + OFF_UNSYM;
  float* out   = (float*)d_out;

  k_stats<<<dim3(NB, NN/16), 256, 0, stream>>>(x, mask, dyn);
  k_node <<<NB*NN, 64, 0, stream>>>(dyn, sctx, W1, b1, W2, b2, We1, be1,
                                    hg, prei, prej, invnp);
  k_pair <<<NB*NN, 256, 0, stream>>>(hg, prei, prej, invnp, coords,
                                     We1, We2, be2, sl, ps, ss, tp, unsym);
  k_sym  <<<NB*NN, 256, 0, stream>>>(unsym, out);
}

// Round 2
// 58.699 us; speedup vs baseline: 3.7331x; 3.7331x over previous
//
#include <hip/hip_runtime.h>
#include <hip/hip_bf16.h>
#include <math.h>

#define NB 2
#define NT 256
#define NN 512
#define NH 64
#define NS 8
#define NC 8

// workspace layout (float offsets)
#define OFF_DYN    0                         // 2*512*4   = 4096
#define OFF_H      4096                      // 2*512*64  = 65536
#define OFF_PVEC   (4096 + 65536)            // 65536   (pre_i + be1)
#define OFF_INVN   (4096 + 2*65536)          // 1024
#define OFF_PRIOR  (4096 + 2*65536 + 1024)   // 512*512 = 262144 (spps*prior, 0 diag)
#define OFF_BFRAG  (OFF_PRIOR + 262144)      // 12288 shorts = 6144 floats
#define OFF_UNSYM  (OFF_BFRAG + 6144)        // 2*512*512 = 524288
// total = 928768 floats ~= 3.55 MB

typedef __attribute__((ext_vector_type(8))) short short8;
typedef __attribute__((ext_vector_type(4))) float f32x4;

__device__ __forceinline__ float softplusf(float x){
  if (x > 20.f) return x;
  return log1pf(expf(x));
}

__device__ __forceinline__ short f2bf(float x){
  __hip_bfloat16 h = __float2bfloat16(x);
  return __builtin_bit_cast(short, h);
}

// ---------------- Kernel P0: convert [Wa;Wp;Wj] -> bf16 MFMA B-fragments ------
// B[k][n], k=0..191: k<64: Wa=We1 rows 128..191 ; k<128: Wp=rows 192..255 ;
// k<192: Wj=rows 64..127.  frag layout: bfrag[((ks*4+nt)*64+lane)*8+e] =
// bf16(B[ks*32+(lane>>4)*8+e][nt*16+(lane&15)])
__global__ __launch_bounds__(256) void k_prep(
    const float* __restrict__ We1, short* __restrict__ bfrag){
  int idx = blockIdx.x * 256 + threadIdx.x;     // 0..12287
  if (idx >= 12288) return;
  int e    = idx & 7;
  int lane = (idx >> 3) & 63;
  int frag = idx >> 9;           // ks*4+nt
  int nt = frag & 3, ks = frag >> 2;
  int k = ks*32 + (lane >> 4)*8 + e;
  int n = nt*16 + (lane & 15);
  int row = (k < 64) ? (128 + k) : (k < 128) ? (192 + (k - 64)) : (64 + (k - 128));
  bfrag[idx] = f2bf(We1[row*NH + n]);
}

// ---------------- Kernel P1: prior matrix, pre-scaled by softplus(ps), 0 diag --
__global__ __launch_bounds__(256) void k_prior(
    const float* __restrict__ coords, const float* __restrict__ ps,
    float* __restrict__ prior_s){
  int idx = blockIdx.x * 256 + threadIdx.x;     // 0..262143
  int i = idx >> 9, j = idx & (NN-1);
  float dd = 0.f;
  #pragma unroll
  for (int d = 0; d < NC; ++d){
    float df = coords[i*NC + d] - coords[j*NC + d];
    dd = fmaf(df, df, dd);
  }
  float dist = sqrtf(fmaxf(dd, 1e-12f));
  float spps = softplusf(ps[0]);
  prior_s[idx] = (i == j) ? 0.f : spps / (1.f + dist);
}

// ---------------- Kernel A: temporal stats -> dyn[b][n][4] ----------------
__global__ __launch_bounds__(256) void k_stats(
    const float* __restrict__ x, const float* __restrict__ mask,
    float* __restrict__ dyn){
  int b  = blockIdx.x;
  int nl = threadIdx.x & 15;
  int ts = threadIdx.x >> 4;
  int n  = blockIdx.y * 16 + nl;

  float cnt = 0.f, sx = 0.f, sxx = 0.f;
  int lastt = 0;
  for (int t = ts*16; t < ts*16 + 16; ++t){
    int idx = (b*NT + t)*NN + n;
    float xv = x[idx];
    float mv = mask[idx];
    bool obs = (mv < 0.5f);
    if (obs){ cnt += 1.f; sx += xv; sxx += xv*xv; lastt = t; }
  }
  __shared__ float s_cnt[16][16], s_sx[16][16], s_sxx[16][16];
  __shared__ int   s_lt[16][16];
  s_cnt[ts][nl] = cnt; s_sx[ts][nl] = sx; s_sxx[ts][nl] = sxx; s_lt[ts][nl] = lastt;
  __syncthreads();
  if (ts == 0){
    for (int s2 = 1; s2 < 16; ++s2){
      cnt += s_cnt[s2][nl]; sx += s_sx[s2][nl]; sxx += s_sxx[s2][nl];
      lastt = max(lastt, s_lt[s2][nl]);
    }
    float cc   = fmaxf(cnt, 1.f);
    float mean = sx / cc;
    float var  = sxx / cc - mean*mean;
    float stdv = sqrtf(fmaxf(var, 0.f) + 1e-6f);
    float last = x[(b*NT + lastt)*NN + n];
    float mr   = 1.f - cnt * (1.f/(float)NT);
    float* o = dyn + ((b*NN) + n)*4;
    o[0] = mean; o[1] = stdv; o[2] = last; o[3] = mr;
  }
}

// ---------------- Kernel B: node MLP -> h, pvec(=pre_i+be1), invn ------------
__global__ __launch_bounds__(64) void k_node(
    const float* __restrict__ dyn, const float* __restrict__ sctx,
    const float* __restrict__ W1, const float* __restrict__ b1,
    const float* __restrict__ W2, const float* __restrict__ b2,
    const float* __restrict__ We1, const float* __restrict__ be1,
    float* __restrict__ hg, float* __restrict__ pvec,
    float* __restrict__ invn){
  int bn = blockIdx.x;
  int n  = bn & (NN-1);
  int c  = threadIdx.x;
  __shared__ float feats[12];
  __shared__ float h1[64];
  __shared__ float h2s[64];
  if (c < 4)       feats[c] = dyn[bn*4 + c];
  else if (c < 12) feats[c] = sctx[n*NS + (c-4)];
  __syncthreads();

  float a = b1[c];
  #pragma unroll
  for (int k = 0; k < 12; ++k) a = fmaf(feats[k], W1[k*NH + c], a);
  h1[c] = fmaxf(a, 0.f);
  __syncthreads();

  float a2 = b2[c];
  #pragma unroll 8
  for (int k = 0; k < 64; ++k) a2 = fmaf(h1[k], W2[k*NH + c], a2);
  a2 = fmaxf(a2, 0.f);

  float sq = a2*a2;
  #pragma unroll
  for (int m = 1; m < 64; m <<= 1) sq += __shfl_xor(sq, m);
  float inv = 1.f / fmaxf(sqrtf(sq), 1e-12f);

  h2s[c] = a2;
  __syncthreads();

  float pi = be1[c];
  #pragma unroll 8
  for (int k = 0; k < 64; ++k) pi = fmaf(h2s[k], We1[k*NH + c], pi);  // Wi rows 0..63

  hg  [bn*64 + c] = a2;
  pvec[bn*64 + c] = pi;
  if (c == 0) invn[bn] = inv;
}

// ---------------- Kernel C: MFMA pairwise edge MLP + logits + row softmax -----
// grid NB*NN (block per (b,i)), 256 thr = 4 waves. Wave handles 16-j tiles
// it = w, w+4, ..., 28 (8 tiles). MFMA 16x16x32 bf16: M=16 j's, N=64 chans
// (4 n-tiles), K=192 feats ([|hi-hj|, hi*hj, hj]) = 6 k-steps.
__global__ __launch_bounds__(256) void k_pair(
    const float* __restrict__ hg, const float* __restrict__ pvec,
    const float* __restrict__ invn, const float* __restrict__ prior_s,
    const short* __restrict__ bfrag,
    const float* __restrict__ We2, const float* __restrict__ be2,
    const float* __restrict__ s_sl, const float* __restrict__ s_ss,
    const float* __restrict__ s_tp,
    float* __restrict__ unsym){
  int blk = blockIdx.x;
  int b = blk >> 9, i = blk & (NN-1);
  int tid  = threadIdx.x;
  int w    = tid >> 6;
  int lane = tid & 63;
  int q    = lane & 15;          // A-row / C-col selector
  int kg   = lane >> 4;          // k-group / C-row-group

  __shared__ __align__(16) float s_hi[64];
  __shared__ __align__(16) float s_pv[64];
  __shared__ __align__(16) float s_prior[NN];
  __shared__ __align__(16) float s_invn[NN];
  __shared__ __align__(16) float lrow[NN];
  __shared__ float red[8];

  if (tid < 64){
    s_hi[tid] = hg  [(b*NN + i)*64 + tid];
    s_pv[tid] = pvec[(b*NN + i)*64 + tid];
  }
  for (int j = tid; j < NN; j += 256){
    s_prior[j] = prior_s[i*NN + j];
    s_invn[j]  = invn[b*NN + j];
  }
  __syncthreads();

  // B fragments: 24 x short8 (96 VGPRs)
  short8 bfr[6][4];
  #pragma unroll
  for (int ks = 0; ks < 6; ++ks)
    #pragma unroll
    for (int nt = 0; nt < 4; ++nt)
      bfr[ks][nt] = *(const short8*)(bfrag + ((ks*4 + nt)*64 + lane)*8);

  // per-lane hi slice: h[kg*8 .. +7] and h[32+kg*8 .. +7]
  float hiA[16];
  {
    float4 t0 = *(const float4*)(s_hi + kg*8);
    float4 t1 = *(const float4*)(s_hi + kg*8 + 4);
    float4 t2 = *(const float4*)(s_hi + 32 + kg*8);
    float4 t3 = *(const float4*)(s_hi + 32 + kg*8 + 4);
    hiA[0]=t0.x; hiA[1]=t0.y; hiA[2]=t0.z; hiA[3]=t0.w;
    hiA[4]=t1.x; hiA[5]=t1.y; hiA[6]=t1.z; hiA[7]=t1.w;
    hiA[8]=t2.x; hiA[9]=t2.y; hiA[10]=t2.z; hiA[11]=t2.w;
    hiA[12]=t3.x; hiA[13]=t3.y; hiA[14]=t3.z; hiA[15]=t3.w;
  }
  float pv4[4], we2q[4];
  #pragma unroll
  for (int nt = 0; nt < 4; ++nt){
    pv4[nt]  = s_pv[nt*16 + q];
    we2q[nt] = We2[nt*16 + q];
  }
  float invni = invn[b*NN + i];
  float be2v  = be2[0];
  float spsl  = softplusf(s_sl[0]);
  float spss  = softplusf(s_ss[0]);
  float invt  = 1.f / (softplusf(s_tp[0]) + 1e-4f);

  // preload first tile's hj
  float4 hj0, hj1, hj2, hj3;
  {
    const float* hjp = hg + (size_t)(b*NN + w*16 + q)*64 + kg*8;
    hj0 = *(const float4*)(hjp);
    hj1 = *(const float4*)(hjp + 4);
    hj2 = *(const float4*)(hjp + 32);
    hj3 = *(const float4*)(hjp + 36);
  }

  for (int it = w; it < 32; it += 4){
    int jbase = it * 16;
    // prefetch next tile
    float4 nj0 = hj0, nj1 = hj1, nj2 = hj2, nj3 = hj3;
    if (it + 4 < 32){
      const float* hjn = hg + (size_t)(b*NN + (it+4)*16 + q)*64 + kg*8;
      nj0 = *(const float4*)(hjn);
      nj1 = *(const float4*)(hjn + 4);
      nj2 = *(const float4*)(hjn + 32);
      nj3 = *(const float4*)(hjn + 36);
    }

    float hjA[16];
    hjA[0]=hj0.x; hjA[1]=hj0.y; hjA[2]=hj0.z; hjA[3]=hj0.w;
    hjA[4]=hj1.x; hjA[5]=hj1.y; hjA[6]=hj1.z; hjA[7]=hj1.w;
    hjA[8]=hj2.x; hjA[9]=hj2.y; hjA[10]=hj2.z; hjA[11]=hj2.w;
    hjA[12]=hj3.x; hjA[13]=hj3.y; hjA[14]=hj3.z; hjA[15]=hj3.w;

    // A fragments + f32 dot partial
    short8 af[6];
    float dotp = 0.f;
    #pragma unroll
    for (int e = 0; e < 8; ++e){
      float p0 = hiA[e]     * hjA[e];
      float p1 = hiA[8 + e] * hjA[8 + e];
      dotp += p0 + p1;
      af[0][e] = f2bf(fabsf(hiA[e]     - hjA[e]));
      af[1][e] = f2bf(fabsf(hiA[8 + e] - hjA[8 + e]));
      af[2][e] = f2bf(p0);
      af[3][e] = f2bf(p1);
      af[4][e] = f2bf(hjA[e]);
      af[5][e] = f2bf(hjA[8 + e]);
    }

    f32x4 acc[4];
    #pragma unroll
    for (int nt = 0; nt < 4; ++nt)
      acc[nt] = (f32x4){pv4[nt], pv4[nt], pv4[nt], pv4[nt]};
    #pragma unroll
    for (int ks = 0; ks < 6; ++ks)
      #pragma unroll
      for (int nt = 0; nt < 4; ++nt)
        acc[nt] = __builtin_amdgcn_mfma_f32_16x16x32_bf16(af[ks], bfr[ks][nt], acc[nt], 0, 0, 0);

    // epilogue: relu + We2 dot, reduce across the 16 q-lanes
    float part[4] = {0.f, 0.f, 0.f, 0.f};
    #pragma unroll
    for (int nt = 0; nt < 4; ++nt)
      #pragma unroll
      for (int r = 0; r < 4; ++r)
        part[r] = fmaf(fmaxf(acc[nt][r], 0.f), we2q[nt], part[r]);
    #pragma unroll
    for (int m = 1; m < 16; m <<= 1){
      #pragma unroll
      for (int r = 0; r < 4; ++r) part[r] += __shfl_xor(part[r], m);
    }
    // dot reduce across kg (each lane then has dot for row q)
    dotp += __shfl_xor(dotp, 16);
    dotp += __shfl_xor(dotp, 32);

    float4 pr4  = *(const float4*)(s_prior + jbase + kg*4);
    float4 inv4 = *(const float4*)(s_invn  + jbase + kg*4);
    float iv[4] = {inv4.x, inv4.y, inv4.z, inv4.w};
    float pr[4] = {pr4.x, pr4.y, pr4.z, pr4.w};
    float lg[4];
    #pragma unroll
    for (int r = 0; r < 4; ++r){
      int j2 = jbase + kg*4 + r;
      float dj   = __shfl(dotp, kg*4 + r);   // lane with q == kg*4+r
      float cosv = dj * invni * iv[r];
      float ev   = part[r] + be2v + pr[r];
      lg[r] = (j2 == i) ? spsl : fmaf(spss, cosv, ev);
    }
    if (q == 0)
      *(float4*)(lrow + jbase + kg*4) = (float4){lg[0], lg[1], lg[2], lg[3]};

    hj0 = nj0; hj1 = nj1; hj2 = nj2; hj3 = nj3;
  }
  __syncthreads();

  // row softmax of lrow * invt
  float m1 = -INFINITY;
  for (int j = tid; j < NN; j += 256) m1 = fmaxf(m1, lrow[j]);
  #pragma unroll
  for (int msk = 1; msk < 64; msk <<= 1) m1 = fmaxf(m1, __shfl_xor(m1, msk));
  if (lane == 0) red[w] = m1;
  __syncthreads();
  m1 = fmaxf(fmaxf(red[0], red[1]), fmaxf(red[2], red[3]));

  float se = 0.f;
  for (int j = tid; j < NN; j += 256){
    float e = expf((lrow[j] - m1) * invt);
    lrow[j] = e;
    se += e;
  }
  #pragma unroll
  for (int msk = 1; msk < 64; msk <<= 1) se += __shfl_xor(se, msk);
  if (lane == 0) red[4 + w] = se;
  __syncthreads();
  se = red[4] + red[5] + red[6] + red[7];
  float inv_se = 1.f / se;

  float* urow = unsym + (size_t)(b*NN + i) * NN;
  for (int j = tid; j < NN; j += 256) urow[j] = lrow[j] * inv_se;
}

// ---------------- Kernel D: symmetrize + renormalize ----------------
__global__ __launch_bounds__(256) void k_sym(
    const float* __restrict__ u, float* __restrict__ out){
  int blk = blockIdx.x;
  int b = blk >> 9, i = blk & (NN-1);
  int tid = threadIdx.x;
  const float* urow = u + (size_t)(b*NN + i) * NN;
  float v0, v1, rs;
  {
    int j0 = tid, j1 = tid + 256;
    float a1 = urow[j0];
    float a2 = u[(size_t)(b*NN + j0) * NN + i];
    v0 = 0.5f*(a1 + a2);
    float a3 = urow[j1];
    float a4 = u[(size_t)(b*NN + j1) * NN + i];
    v1 = 0.5f*(a3 + a4);
    rs = v0 + v1;
  }
  int lane = tid & 63, w = tid >> 6;
  #pragma unroll
  for (int msk = 1; msk < 64; msk <<= 1) rs += __shfl_xor(rs, msk);
  __shared__ float red[4];
  if (lane == 0) red[w] = rs;
  __syncthreads();
  rs = red[0] + red[1] + red[2] + red[3];
  float inv = 1.f / fmaxf(rs, 1e-6f);
  float* orow = out + (size_t)(b*NN + i) * NN;
  orow[tid]       = v0 * inv;
  orow[tid + 256] = v1 * inv;
}

extern "C" void kernel_launch(void* const* d_in, const int* in_sizes, int n_in,
                              void* d_out, int out_size, void* d_ws, size_t ws_size,
                              hipStream_t stream){
  const float* x      = (const float*)d_in[0];
  const float* mask   = (const float*)d_in[1];
  const float* sctx   = (const float*)d_in[2];
  const float* coords = (const float*)d_in[3];
  const float* W1     = (const float*)d_in[4];
  const float* b1     = (const float*)d_in[5];
  const float* W2     = (const float*)d_in[6];
  const float* b2     = (const float*)d_in[7];
  const float* We1    = (const float*)d_in[8];
  const float* be1    = (const float*)d_in[9];
  const float* We2    = (const float*)d_in[10];
  const float* be2    = (const float*)d_in[11];
  const float* sl     = (const float*)d_in[12];
  const float* ps     = (const float*)d_in[13];
  const float* ss     = (const float*)d_in[14];
  const float* tp     = (const float*)d_in[15];

  float* ws     = (float*)d_ws;
  float* dyn    = ws + OFF_DYN;
  float* hg     = ws + OFF_H;
  float* pvec   = ws + OFF_PVEC;
  float* invnp  = ws + OFF_INVN;
  float* priorp = ws + OFF_PRIOR;
  short* bfragp = (short*)(ws + OFF_BFRAG);
  float* unsym  = ws + OFF_UNSYM;
  float* out    = (float*)d_out;

  k_prep <<<48, 256, 0, stream>>>(We1, bfragp);
  k_prior<<<NN*NN/256, 256, 0, stream>>>(coords, ps, priorp);
  k_stats<<<dim3(NB, NN/16), 256, 0, stream>>>(x, mask, dyn);
  k_node <<<NB*NN, 64, 0, stream>>>(dyn, sctx, W1, b1, W2, b2, We1, be1,
                                    hg, pvec, invnp);
  k_pair <<<NB*NN, 256, 0, stream>>>(hg, pvec, invnp, priorp, bfragp,
                                     We2, be2, sl, ss, tp, unsym);
  k_sym  <<<NB*NN, 256, 0, stream>>>(unsym, out);
}